// Round 6
// baseline (231.459 us; speedup 1.0000x reference)
//
#include <hip/hip_runtime.h>
#include <hip/hip_bf16.h>

// N=100000, E=3200000, C=4, H=64. f32 inputs; edge_index int32;
// output concat(pm10_next[N], delta[N]) f32.
//
// R6 pipeline (no global f32 atomics on the steady path):
//  prep    : pack x(4f)+pos(2f) into 32B xpos rows (1 cache line per gather)
//  init    : zero pair-packed bucket counters + ovf counter
//  scatter : hist(dst>>8) -> paired u64 global reservation -> scatter
//            payload u32 = (src<<8)|(dst&255). No MLP here.
//  compute : 4 blocks per 256-node bucket; coalesced payload reads;
//            xpos[src] gathers are L2-resident (3.2MB), xpos[dst] gathers are
//            bucket-local (8KB, L1); VALU MLP (wave-uniform weight loads);
//            ds_add_f32 into acc[256]; write per-part partials (plain stores).
//  ovf     : rare overflow edges -> delta_extra (f32 atomics, ~0 edges)
//  final   : delta = sum of 4 partials + delta_extra + head_b; softplus; store.

#define HID    64
#define EPSV   1e-8f
#define BNODES 256
#define CAP    10240        // mean 8192, sigma ~90 -> +22 sigma
#define MAXB   512
#define NB_SC  256          // scatter grid
#define BLK_SC 512
#define KPART  4            // blocks per bucket in compute
#define BLK_C  512
#define OVF_CAP 65536

__device__ __forceinline__ void feat_from_rows(float4 xs, float4 ps4,
                                               float4 xd, float4 pd4,
                                               float* f) {
    float d0 = ps4.x - pd4.x;
    float d1 = ps4.y - pd4.y;
    float dist = sqrtf(fmaf(d0, d0, fmaf(d1, d1, EPSV)));
    float inv = 1.0f / dist;
    float wind = (xs.y * d0 + xs.z * d1) * inv;
    f[0] = xd.x; f[1] = xd.y; f[2] = xd.z; f[3] = xd.w;
    f[4] = xs.x; f[5] = xs.y; f[6] = xs.z; f[7] = xs.w;
    f[8] = wind; f[9] = dist;
}

__device__ __forceinline__ float mlp_scalar_g(const float* __restrict__ mlp_w,
                                              const float* __restrict__ mlp_b,
                                              const float* __restrict__ head_w,
                                              const float* f) {
    float sacc = 0.0f;
    for (int h = 0; h < HID; h++) {
        const float* wr = mlp_w + h * 10;
        float a = mlp_b[h];
        a = fmaf(wr[0], f[0], a); a = fmaf(wr[1], f[1], a);
        a = fmaf(wr[2], f[2], a); a = fmaf(wr[3], f[3], a);
        a = fmaf(wr[4], f[4], a); a = fmaf(wr[5], f[5], a);
        a = fmaf(wr[6], f[6], a); a = fmaf(wr[7], f[7], a);
        a = fmaf(wr[8], f[8], a); a = fmaf(wr[9], f[9], a);
        a = fmaxf(a, 0.0f);
        sacc = fmaf(head_w[h], a, sacc);
    }
    return sacc;
}

// ---------------- prep: pack 32B rows ----------------
__global__ __launch_bounds__(512) void prep_kernel(
    const float4* __restrict__ x, const float2* __restrict__ pos,
    float4* __restrict__ xpos, int N)
{
    int n = blockIdx.x * 512 + threadIdx.x;
    if (n >= N) return;
    float4 xr = x[n];
    float2 pr = pos[n];
    xpos[2 * n]     = xr;
    xpos[2 * n + 1] = make_float4(pr.x, pr.y, 0.0f, 0.0f);
}

__global__ void init_kernel(unsigned long long* g_ptr64, int* ovf_cnt, int PB) {
    int t = blockIdx.x * blockDim.x + threadIdx.x;
    if (t < PB) g_ptr64[t] = 0ull;
    if (t == 0) *ovf_cnt = 0;
}

// ---------------- scatter (no MLP) ----------------
__global__ __launch_bounds__(BLK_SC) void scatter_kernel(
    const int* __restrict__ srcs, const int* __restrict__ dsts,
    int E, int B, int chunk,
    unsigned long long* g_ptr64, unsigned int* __restrict__ sorted,
    int2* __restrict__ ovf, int* ovf_cnt)
{
    __shared__ int hist[MAXB];
    __shared__ int base[MAXB];
    __shared__ int run[MAXB];
    int tid = threadIdx.x;
    int lo = blockIdx.x * chunk;
    int hi = min(E, lo + chunk);

    for (int b = tid; b < B; b += BLK_SC) { hist[b] = 0; run[b] = 0; }
    __syncthreads();
    for (int e = lo + tid; e < hi; e += BLK_SC)
        atomicAdd(&hist[dsts[e] >> 8], 1);
    __syncthreads();
    int PB = (B + 1) >> 1;
    for (int p = tid; p < PB; p += BLK_SC) {
        int b0 = 2 * p, b1 = 2 * p + 1;
        unsigned long long h0 = (unsigned int)hist[b0];
        unsigned long long h1 = (b1 < B) ? (unsigned int)hist[b1] : 0ull;
        unsigned long long comb = h0 | (h1 << 32);
        unsigned long long old = 0ull;
        if (comb) old = atomicAdd(&g_ptr64[p], comb);
        base[b0] = (int)(old & 0xffffffffull);
        if (b1 < B) base[b1] = (int)(old >> 32);
    }
    __syncthreads();

    for (int e = lo + tid; e < hi; e += BLK_SC) {
        int s = srcs[e];
        int d = dsts[e];
        int b = d >> 8;
        int rk = atomicAdd(&run[b], 1);          // LDS, on-chip
        int rel = base[b] + rk;
        unsigned int pay = ((unsigned int)s << 8) | (unsigned int)(d & 255);
        if (rel < CAP) {
            sorted[(size_t)b * CAP + rel] = pay;
        } else {
            int o = atomicAdd(ovf_cnt, 1);
            if (o < OVF_CAP) ovf[o] = make_int2(s, d);
        }
    }
}

// ---------------- compute + per-part reduce (atomic-free) ----------------
__global__ __launch_bounds__(BLK_C) void compute_kernel(
    const float4* __restrict__ xpos,
    const float* __restrict__ mlp_w, const float* __restrict__ mlp_b,
    const float* __restrict__ head_w,
    const unsigned int* __restrict__ sorted,
    const unsigned long long* __restrict__ g_ptr64,
    float* __restrict__ partial, int BB)
{
    __shared__ float acc[BNODES];
    int tid = threadIdx.x;
    int b    = blockIdx.x >> 2;
    int part = blockIdx.x & 3;
    if (tid < BNODES) acc[tid] = 0.0f;
    __syncthreads();

    unsigned long long gp = g_ptr64[b >> 1];
    int cnt = (b & 1) ? (int)(gp >> 32) : (int)(gp & 0xffffffffull);
    cnt = min(cnt, CAP);
    int e0 = (cnt * part) >> 2;
    int e1 = (cnt * (part + 1)) >> 2;
    const unsigned int* sp = sorted + (size_t)b * CAP;
    int nbase = b << 8;

    for (int i0 = e0; i0 < e1; i0 += 2 * BLK_C) {
        float f[2][10];
        int   dl[2];
        bool  val[2];
        #pragma unroll
        for (int r = 0; r < 2; r++) {
            int i = i0 + r * BLK_C + tid;
            bool ok = (i < e1);
            val[r] = ok;
            unsigned int pay = sp[ok ? i : e0];
            int s = (int)(pay >> 8);
            int d = nbase + (int)(pay & 255u);
            dl[r] = (int)(pay & 255u);
            float4 xs  = xpos[2 * s];
            float4 ps4 = xpos[2 * s + 1];
            float4 xd  = xpos[2 * d];       // bucket-local: 8KB window, L1
            float4 pd4 = xpos[2 * d + 1];
            feat_from_rows(xs, ps4, xd, pd4, f[r]);
        }

        float sacc[2] = {0.0f, 0.0f};
        for (int h = 0; h < HID; h++) {
            const float* wr = mlp_w + h * 10;   // wave-uniform -> s_load/K$
            float w0 = wr[0], w1 = wr[1], w2 = wr[2], w3 = wr[3], w4 = wr[4];
            float w5 = wr[5], w6 = wr[6], w7 = wr[7], w8 = wr[8], w9 = wr[9];
            float bb = mlp_b[h];
            float hw = head_w[h];
            #pragma unroll
            for (int r = 0; r < 2; r++) {
                float a = bb;
                a = fmaf(w0, f[r][0], a); a = fmaf(w1, f[r][1], a);
                a = fmaf(w2, f[r][2], a); a = fmaf(w3, f[r][3], a);
                a = fmaf(w4, f[r][4], a); a = fmaf(w5, f[r][5], a);
                a = fmaf(w6, f[r][6], a); a = fmaf(w7, f[r][7], a);
                a = fmaf(w8, f[r][8], a); a = fmaf(w9, f[r][9], a);
                a = fmaxf(a, 0.0f);
                sacc[r] = fmaf(hw, a, sacc[r]);
            }
        }
        #pragma unroll
        for (int r = 0; r < 2; r++)
            if (val[r]) atomicAdd(&acc[dl[r]], sacc[r]);   // ds_add_f32
    }
    __syncthreads();
    if (tid < BNODES)
        partial[(size_t)part * BB + nbase + tid] = acc[tid];
}

// ---------------- overflow cleanup (normally 0 edges) ----------------
__global__ __launch_bounds__(256) void ovf_kernel(
    const float4* __restrict__ x, const float2* __restrict__ pos,
    const float* __restrict__ mlp_w, const float* __restrict__ mlp_b,
    const float* __restrict__ head_w,
    const int2* __restrict__ ovf, const int* __restrict__ ovf_cnt,
    float* __restrict__ delta_extra)
{
    int cnt = min(*ovf_cnt, OVF_CAP);
    for (int i = blockIdx.x * blockDim.x + threadIdx.x; i < cnt;
         i += gridDim.x * blockDim.x) {
        int2 sd = ovf[i];
        float4 xs = x[sd.x], xd = x[sd.y];
        float2 ps = pos[sd.x], pd = pos[sd.y];
        float f[10];
        feat_from_rows(xs, make_float4(ps.x, ps.y, 0, 0),
                       xd, make_float4(pd.x, pd.y, 0, 0), f);
        unsafeAtomicAdd(&delta_extra[sd.y], mlp_scalar_g(mlp_w, mlp_b, head_w, f));
    }
}

// ---------------- final: sum partials + epilogue ----------------
__global__ __launch_bounds__(512) void final_kernel(
    const float* __restrict__ xf,            // x flat f32, stride 4
    const float* __restrict__ partial, int BB,
    const float* __restrict__ delta_extra,
    const float* __restrict__ head_b,
    float* __restrict__ out, int N)
{
    int n = blockIdx.x * 512 + threadIdx.x;
    if (n >= N) return;
    float delta = partial[n] + partial[(size_t)BB + n]
                + partial[2 * (size_t)BB + n] + partial[3 * (size_t)BB + n]
                + delta_extra[n] + head_b[0];
    float v = xf[4 * n] + delta;
    float sp = fmaxf(v, 0.0f) + log1pf(expf(-fabsf(v)));
    out[n] = sp;
    out[N + n] = delta;
}

// ---------------- fallback path (ws too small) ----------------
__global__ __launch_bounds__(256) void edge_kernel_fallback(
    const float4* __restrict__ x, const float2* __restrict__ pos,
    const float* __restrict__ mlp_w, const float* __restrict__ mlp_b,
    const float* __restrict__ head_w,
    const int* __restrict__ srcs, const int* __restrict__ dsts,
    float* __restrict__ delta_acc, int E)
{
    int tid = threadIdx.x;
    long e = (long)blockIdx.x * 256 + tid;
    if (e >= E) return;
    int s = srcs[e], d = dsts[e];
    float4 xs = x[s], xd = x[d];
    float2 ps = pos[s], pd = pos[d];
    float f[10];
    feat_from_rows(xs, make_float4(ps.x, ps.y, 0, 0),
                   xd, make_float4(pd.x, pd.y, 0, 0), f);
    unsafeAtomicAdd(&delta_acc[d], mlp_scalar_g(mlp_w, mlp_b, head_w, f));
}

__global__ __launch_bounds__(256) void node_kernel_fallback(
    const float* __restrict__ xf, const float* __restrict__ delta_acc,
    const float* __restrict__ head_b, float* __restrict__ out, int N)
{
    int n = blockIdx.x * 256 + threadIdx.x;
    if (n >= N) return;
    float delta = delta_acc[n] + head_b[0];
    float v = xf[4 * n] + delta;
    float sp = fmaxf(v, 0.0f) + log1pf(expf(-fabsf(v)));
    out[n] = sp;
    out[N + n] = delta;
}

// ---------------- host ----------------
static inline size_t align_up(size_t v, size_t a) { return (v + a - 1) & ~(a - 1); }

extern "C" void kernel_launch(void* const* d_in, const int* in_sizes, int n_in,
                              void* d_out, int out_size, void* d_ws, size_t ws_size,
                              hipStream_t stream) {
    const float4* x      = (const float4*)d_in[0];
    const float2* pos    = (const float2*)d_in[1];
    const float*  mlp_w  = (const float*)d_in[2];
    const float*  mlp_b  = (const float*)d_in[3];
    const float*  head_w = (const float*)d_in[4];
    const float*  head_b = (const float*)d_in[5];
    const int*    ei     = (const int*)d_in[6];

    int N = in_sizes[0] / 4;   // 100000
    int E = in_sizes[6] / 2;   // 3200000
    const int* srcs = ei;
    const int* dsts = ei + E;
    int B  = (N + BNODES - 1) / BNODES;   // 391
    int PB = (B + 1) >> 1;                // 196
    int BB = B * BNODES;                  // 100096

    size_t off = 0;
    float* delta_extra = (float*)((char*)d_ws + off);
    off = align_up(off + (size_t)N * 4, 256);
    float4* xpos = (float4*)((char*)d_ws + off);
    off = align_up(off + (size_t)N * 32, 256);
    unsigned long long* g_ptr64 = (unsigned long long*)((char*)d_ws + off);
    off = align_up(off + (size_t)PB * 8, 256);
    int* ovf_cnt = (int*)((char*)d_ws + off);
    off = align_up(off + 64, 256);
    int2* ovf = (int2*)((char*)d_ws + off);
    off = align_up(off + (size_t)OVF_CAP * 8, 256);
    float* partial = (float*)((char*)d_ws + off);
    off = align_up(off + (size_t)KPART * BB * 4, 256);
    unsigned int* sorted = (unsigned int*)((char*)d_ws + off);
    off = align_up(off + (size_t)B * CAP * 4, 256);
    bool fast = (off <= ws_size) && (B <= MAXB);

    if (fast) {
        hipMemsetAsync(delta_extra, 0, (size_t)N * sizeof(float), stream);
        prep_kernel<<<(N + 511) / 512, 512, 0, stream>>>(x, pos, xpos, N);
        init_kernel<<<(PB + 255) / 256, 256, 0, stream>>>(g_ptr64, ovf_cnt, PB);
        int chunk = (E + NB_SC - 1) / NB_SC;
        scatter_kernel<<<NB_SC, BLK_SC, 0, stream>>>(srcs, dsts, E, B, chunk,
                                                     g_ptr64, sorted, ovf, ovf_cnt);
        compute_kernel<<<KPART * B, BLK_C, 0, stream>>>(xpos, mlp_w, mlp_b, head_w,
                                                        sorted, g_ptr64, partial, BB);
        ovf_kernel<<<16, 256, 0, stream>>>(x, pos, mlp_w, mlp_b, head_w,
                                           ovf, ovf_cnt, delta_extra);
        final_kernel<<<(N + 511) / 512, 512, 0, stream>>>(
            (const float*)x, partial, BB, delta_extra, head_b, (float*)d_out, N);
    } else {
        float* delta = (float*)d_ws;
        hipMemsetAsync(delta, 0, (size_t)N * sizeof(float), stream);
        edge_kernel_fallback<<<(int)((E + 255) / 256), 256, 0, stream>>>(
            x, pos, mlp_w, mlp_b, head_w, srcs, dsts, delta, E);
        node_kernel_fallback<<<(N + 255) / 256, 256, 0, stream>>>(
            (const float*)x, delta, head_b, (float*)d_out, N);
    }
}

// Round 7
// 187.628 us; speedup vs baseline: 1.2336x; 1.2336x over previous
//
#include <hip/hip_runtime.h>
#include <hip/hip_bf16.h>

// N=100000, E=3200000, C=4, H=64. f32 inputs; edge_index int32;
// output concat(pm10_next[N], delta[N]) f32.
//
// R7: MFMA compute. Pipeline:
//  prep    : pack x+pos into 32B xpos rows; zero delta_extra; init counters
//  scatter : single global read (edges held in VGPRs across hist barrier),
//            LDS hist -> u64-paired global reservation -> rank via LDS
//            atomic -> payload u32 = (src<<8)|(dst&255)
//  compute : per bucket (256 dst nodes) x KPART blocks. Per wave-iter:
//            64 edges -> f32 features -> f16 pack -> LDS A-stage (80B/slot) ->
//            4 sub-groups x 4 mfma_f32_16x16x32_f16 (C = bias) -> relu*hw ->
//            shfl_xor column reduce -> ds_add acc[256]. No global atomics.
//  ovf     : statistically-never overflow edges (f32 path)
//  final   : delta = sum KPART partials + extra + head_b; softplus; store.

#define HID    64
#define EPSV   1e-8f
#define BNODES 256
#define CAP    10240        // mean 8192, sigma ~90 -> +22 sigma
#define MAXB   512
#define BLK_SC 512
#define RPT_SC 25           // edges held per scatter thread
#define KPART  4
#define BLK_C  256
#define SLOTW  20           // dwords per staged edge slot (80B, 16B aligned)
#define OVF_CAP 65536

typedef _Float16 half8 __attribute__((ext_vector_type(8)));
typedef _Float16 half2_t __attribute__((ext_vector_type(2)));
typedef float f32x4 __attribute__((ext_vector_type(4)));

__device__ __forceinline__ unsigned int packh2(float a, float b) {
    union { half2_t h; unsigned int u; } v;
    v.h = half2_t{(_Float16)a, (_Float16)b};
    return v.u;
}

__device__ __forceinline__ void feat_from_rows(float4 xs, float4 ps4,
                                               float4 xd, float4 pd4,
                                               float* f) {
    float d0 = ps4.x - pd4.x;
    float d1 = ps4.y - pd4.y;
    float dist = sqrtf(fmaf(d0, d0, fmaf(d1, d1, EPSV)));
    float inv = 1.0f / dist;
    float wind = (xs.y * d0 + xs.z * d1) * inv;
    f[0] = xd.x; f[1] = xd.y; f[2] = xd.z; f[3] = xd.w;
    f[4] = xs.x; f[5] = xs.y; f[6] = xs.z; f[7] = xs.w;
    f[8] = wind; f[9] = dist;
}

__device__ __forceinline__ float mlp_scalar_g(const float* __restrict__ mlp_w,
                                              const float* __restrict__ mlp_b,
                                              const float* __restrict__ head_w,
                                              const float* f) {
    float sacc = 0.0f;
    for (int h = 0; h < HID; h++) {
        const float* wr = mlp_w + h * 10;
        float a = mlp_b[h];
        a = fmaf(wr[0], f[0], a); a = fmaf(wr[1], f[1], a);
        a = fmaf(wr[2], f[2], a); a = fmaf(wr[3], f[3], a);
        a = fmaf(wr[4], f[4], a); a = fmaf(wr[5], f[5], a);
        a = fmaf(wr[6], f[6], a); a = fmaf(wr[7], f[7], a);
        a = fmaf(wr[8], f[8], a); a = fmaf(wr[9], f[9], a);
        a = fmaxf(a, 0.0f);
        sacc = fmaf(head_w[h], a, sacc);
    }
    return sacc;
}

// ---------------- prep: pack rows + zero everything ----------------
__global__ __launch_bounds__(512) void prep_kernel(
    const float4* __restrict__ x, const float2* __restrict__ pos,
    float4* __restrict__ xpos, float* __restrict__ delta_extra,
    unsigned long long* g_ptr64, int* ovf_cnt, int N, int PB)
{
    int n = blockIdx.x * 512 + threadIdx.x;
    if (n < N) {
        float4 xr = x[n];
        float2 pr = pos[n];
        xpos[2 * n]     = xr;
        xpos[2 * n + 1] = make_float4(pr.x, pr.y, 0.0f, 0.0f);
        delta_extra[n] = 0.0f;
    }
    if (n < PB) g_ptr64[n] = 0ull;
    if (n == 0) *ovf_cnt = 0;
}

// ---------------- scatter: one global read, regs across barrier ----------------
__global__ __launch_bounds__(BLK_SC) void scatter_kernel(
    const int* __restrict__ srcs, const int* __restrict__ dsts,
    int E, int B,
    unsigned long long* g_ptr64, unsigned int* __restrict__ sorted,
    int2* __restrict__ ovf, int* ovf_cnt)
{
    __shared__ int hist[MAXB];
    __shared__ int base[MAXB];
    __shared__ int run[MAXB];
    int tid = threadIdx.x;
    int lo = blockIdx.x * (BLK_SC * RPT_SC);

    int es[RPT_SC], ed[RPT_SC];
    bool ev[RPT_SC];
    #pragma unroll
    for (int r = 0; r < RPT_SC; r++) {
        int e = lo + r * BLK_SC + tid;
        bool ok = (e < E);
        ev[r] = ok;
        int ee = ok ? e : 0;
        es[r] = srcs[ee];
        ed[r] = dsts[ee];
    }

    for (int b = tid; b < B; b += BLK_SC) { hist[b] = 0; run[b] = 0; }
    __syncthreads();
    #pragma unroll
    for (int r = 0; r < RPT_SC; r++)
        if (ev[r]) atomicAdd(&hist[ed[r] >> 8], 1);
    __syncthreads();
    int PB = (B + 1) >> 1;
    for (int p = tid; p < PB; p += BLK_SC) {
        int b0 = 2 * p, b1 = 2 * p + 1;
        unsigned long long h0 = (unsigned int)hist[b0];
        unsigned long long h1 = (b1 < B) ? (unsigned int)hist[b1] : 0ull;
        unsigned long long comb = h0 | (h1 << 32);
        unsigned long long old = 0ull;
        if (comb) old = atomicAdd(&g_ptr64[p], comb);
        base[b0] = (int)(old & 0xffffffffull);
        if (b1 < B) base[b1] = (int)(old >> 32);
    }
    __syncthreads();

    #pragma unroll
    for (int r = 0; r < RPT_SC; r++) {
        if (ev[r]) {
            int d = ed[r];
            int b = d >> 8;
            int rk = atomicAdd(&run[b], 1);      // LDS, on-chip
            int rel = base[b] + rk;
            unsigned int pay = ((unsigned int)es[r] << 8) | (unsigned int)(d & 255);
            if (rel < CAP) {
                sorted[(size_t)b * CAP + rel] = pay;
            } else {
                int o = atomicAdd(ovf_cnt, 1);
                if (o < OVF_CAP) ovf[o] = make_int2(es[r], d);
            }
        }
    }
}

// ---------------- compute: MFMA MLP + bucket reduce ----------------
__global__ __launch_bounds__(BLK_C, 4) void compute_kernel(
    const float4* __restrict__ xpos,
    const float* __restrict__ mlp_w, const float* __restrict__ mlp_b,
    const float* __restrict__ head_w,
    const unsigned int* __restrict__ sorted,
    const unsigned long long* __restrict__ g_ptr64,
    float* __restrict__ partial, int BB)
{
    // Per-wave A staging: 64 slots x 20 dwords (80B, 16B aligned). Dwords:
    // 0-4: f16x2 features k0..k9; 5-15: zeros (k10..k31); 16: reduced sum.
    __shared__ __align__(16) unsigned int stage[4 * 64 * SLOTW];
    __shared__ float acc[BNODES];
    int tid  = threadIdx.x;
    int wave = tid >> 6;
    int lane = tid & 63;
    int col  = lane & 15;
    int quad = lane >> 4;
    int wbase = wave * 64 * SLOTW;

    acc[tid] = 0.0f;

    // zero the static-zero region of this lane's slot (once)
    {
        unsigned int* slotp = &stage[wbase + lane * SLOTW];
        slotp[5] = 0u;
        *(uint2*)(slotp + 6) = make_uint2(0u, 0u);
        *(uint4*)(slotp + 8) = make_uint4(0u, 0u, 0u, 0u);
        *(uint4*)(slotp + 12) = make_uint4(0u, 0u, 0u, 0u);
    }

    // Weight fragments: B[k=quad*8+j][n=col] for hid chunk c -> h=c*16+col.
    half8 bfr[4];
    float bias[4], hw[4];
    #pragma unroll
    for (int c = 0; c < 4; c++) {
        int h = c * 16 + col;
        half8 bf = half8{0, 0, 0, 0, 0, 0, 0, 0};
        if (quad == 0) {
            #pragma unroll
            for (int j = 0; j < 8; j++) bf[j] = (_Float16)mlp_w[h * 10 + j];
        } else if (quad == 1) {
            bf[0] = (_Float16)mlp_w[h * 10 + 8];
            bf[1] = (_Float16)mlp_w[h * 10 + 9];
        }
        bfr[c] = bf;
        bias[c] = mlp_b[h];
        hw[c] = head_w[h];
    }
    __syncthreads();

    int b    = blockIdx.x >> 2;
    int part = blockIdx.x & 3;
    unsigned long long gp = g_ptr64[b >> 1];
    int cnt = (b & 1) ? (int)(gp >> 32) : (int)(gp & 0xffffffffull);
    cnt = min(cnt, CAP);
    int e0 = (cnt * part) >> 2;
    int e1 = (cnt * (part + 1)) >> 2;
    const unsigned int* sp = sorted + (size_t)b * CAP;
    int nbase = b << 8;

    for (int i0 = e0; i0 < e1; i0 += BLK_C) {
        int i = i0 + tid;
        bool ok = (i < e1);
        unsigned int pay = sp[ok ? i : e0];
        int s  = (int)(pay >> 8);
        int dl = (int)(pay & 255u);
        float4 xs  = xpos[2 * s];
        float4 ps4 = xpos[2 * s + 1];
        float4 xd  = xpos[2 * (nbase + dl)];
        float4 pd4 = xpos[2 * (nbase + dl) + 1];
        float f[10];
        feat_from_rows(xs, ps4, xd, pd4, f);

        unsigned int* slotp = &stage[wbase + lane * SLOTW];
        *(uint4*)slotp = make_uint4(packh2(f[0], f[1]), packh2(f[2], f[3]),
                                    packh2(f[4], f[5]), packh2(f[6], f[7]));
        slotp[4] = packh2(f[8], f[9]);

        #pragma unroll
        for (int sg = 0; sg < 4; sg++) {
            const half8 a = *(const half8*)&stage[wbase + (sg * 16 + col) * SLOTW + quad * 4];
            float p0 = 0.f, p1 = 0.f, p2 = 0.f, p3 = 0.f;
            #pragma unroll
            for (int c = 0; c < 4; c++) {
                f32x4 cb = f32x4{bias[c], bias[c], bias[c], bias[c]};
                f32x4 d = __builtin_amdgcn_mfma_f32_16x16x32_f16(a, bfr[c], cb, 0, 0, 0);
                p0 = fmaf(hw[c], fmaxf(d[0], 0.f), p0);
                p1 = fmaf(hw[c], fmaxf(d[1], 0.f), p1);
                p2 = fmaf(hw[c], fmaxf(d[2], 0.f), p2);
                p3 = fmaf(hw[c], fmaxf(d[3], 0.f), p3);
            }
            #pragma unroll
            for (int m = 1; m <= 8; m <<= 1) {
                p0 += __shfl_xor(p0, m, 64);
                p1 += __shfl_xor(p1, m, 64);
                p2 += __shfl_xor(p2, m, 64);
                p3 += __shfl_xor(p3, m, 64);
            }
            if (col == 0) {   // writer lane per quad: slots sg*16 + 4*quad + r
                unsigned int bdw = wbase + (sg * 16 + quad * 4) * SLOTW + 16;
                stage[bdw]             = __float_as_uint(p0);
                stage[bdw + SLOTW]     = __float_as_uint(p1);
                stage[bdw + 2 * SLOTW] = __float_as_uint(p2);
                stage[bdw + 3 * SLOTW] = __float_as_uint(p3);
            }
        }
        float mysum = __uint_as_float(stage[wbase + lane * SLOTW + 16]);
        if (ok) atomicAdd(&acc[dl], mysum);   // ds_add_f32
    }
    __syncthreads();
    partial[(size_t)part * BB + nbase + tid] = acc[tid];
}

// ---------------- overflow cleanup (normally 0 edges) ----------------
__global__ __launch_bounds__(256) void ovf_kernel(
    const float4* __restrict__ x, const float2* __restrict__ pos,
    const float* __restrict__ mlp_w, const float* __restrict__ mlp_b,
    const float* __restrict__ head_w,
    const int2* __restrict__ ovf, const int* __restrict__ ovf_cnt,
    float* __restrict__ delta_extra)
{
    int cnt = min(*ovf_cnt, OVF_CAP);
    for (int i = blockIdx.x * blockDim.x + threadIdx.x; i < cnt;
         i += gridDim.x * blockDim.x) {
        int2 sd = ovf[i];
        float4 xs = x[sd.x], xd = x[sd.y];
        float2 ps = pos[sd.x], pd = pos[sd.y];
        float f[10];
        feat_from_rows(xs, make_float4(ps.x, ps.y, 0, 0),
                       xd, make_float4(pd.x, pd.y, 0, 0), f);
        unsafeAtomicAdd(&delta_extra[sd.y], mlp_scalar_g(mlp_w, mlp_b, head_w, f));
    }
}

// ---------------- final: sum partials + epilogue ----------------
__global__ __launch_bounds__(512) void final_kernel(
    const float* __restrict__ xf,
    const float* __restrict__ partial, int BB,
    const float* __restrict__ delta_extra,
    const float* __restrict__ head_b,
    float* __restrict__ out, int N)
{
    int n = blockIdx.x * 512 + threadIdx.x;
    if (n >= N) return;
    float delta = partial[n] + partial[(size_t)BB + n]
                + partial[2 * (size_t)BB + n] + partial[3 * (size_t)BB + n]
                + delta_extra[n] + head_b[0];
    float v = xf[4 * n] + delta;
    float sp = fmaxf(v, 0.0f) + log1pf(expf(-fabsf(v)));
    out[n] = sp;
    out[N + n] = delta;
}

// ---------------- fallback path (ws too small) ----------------
__global__ __launch_bounds__(256) void edge_kernel_fallback(
    const float4* __restrict__ x, const float2* __restrict__ pos,
    const float* __restrict__ mlp_w, const float* __restrict__ mlp_b,
    const float* __restrict__ head_w,
    const int* __restrict__ srcs, const int* __restrict__ dsts,
    float* __restrict__ delta_acc, int E)
{
    long e = (long)blockIdx.x * 256 + threadIdx.x;
    if (e >= E) return;
    int s = srcs[e], d = dsts[e];
    float4 xs = x[s], xd = x[d];
    float2 ps = pos[s], pd = pos[d];
    float f[10];
    feat_from_rows(xs, make_float4(ps.x, ps.y, 0, 0),
                   xd, make_float4(pd.x, pd.y, 0, 0), f);
    unsafeAtomicAdd(&delta_acc[d], mlp_scalar_g(mlp_w, mlp_b, head_w, f));
}

__global__ __launch_bounds__(256) void node_kernel_fallback(
    const float* __restrict__ xf, const float* __restrict__ delta_acc,
    const float* __restrict__ head_b, float* __restrict__ out, int N)
{
    int n = blockIdx.x * 256 + threadIdx.x;
    if (n >= N) return;
    float delta = delta_acc[n] + head_b[0];
    float v = xf[4 * n] + delta;
    float sp = fmaxf(v, 0.0f) + log1pf(expf(-fabsf(v)));
    out[n] = sp;
    out[N + n] = delta;
}

// ---------------- host ----------------
static inline size_t align_up(size_t v, size_t a) { return (v + a - 1) & ~(a - 1); }

extern "C" void kernel_launch(void* const* d_in, const int* in_sizes, int n_in,
                              void* d_out, int out_size, void* d_ws, size_t ws_size,
                              hipStream_t stream) {
    const float4* x      = (const float4*)d_in[0];
    const float2* pos    = (const float2*)d_in[1];
    const float*  mlp_w  = (const float*)d_in[2];
    const float*  mlp_b  = (const float*)d_in[3];
    const float*  head_w = (const float*)d_in[4];
    const float*  head_b = (const float*)d_in[5];
    const int*    ei     = (const int*)d_in[6];

    int N = in_sizes[0] / 4;   // 100000
    int E = in_sizes[6] / 2;   // 3200000
    const int* srcs = ei;
    const int* dsts = ei + E;
    int B  = (N + BNODES - 1) / BNODES;   // 391
    int PB = (B + 1) >> 1;                // 196
    int BB = B * BNODES;                  // 100096

    size_t off = 0;
    float* delta_extra = (float*)((char*)d_ws + off);
    off = align_up(off + (size_t)N * 4, 256);
    float4* xpos = (float4*)((char*)d_ws + off);
    off = align_up(off + (size_t)N * 32, 256);
    unsigned long long* g_ptr64 = (unsigned long long*)((char*)d_ws + off);
    off = align_up(off + (size_t)PB * 8, 256);
    int* ovf_cnt = (int*)((char*)d_ws + off);
    off = align_up(off + 64, 256);
    int2* ovf = (int2*)((char*)d_ws + off);
    off = align_up(off + (size_t)OVF_CAP * 8, 256);
    float* partial = (float*)((char*)d_ws + off);
    off = align_up(off + (size_t)KPART * BB * 4, 256);
    unsigned int* sorted = (unsigned int*)((char*)d_ws + off);
    off = align_up(off + (size_t)B * CAP * 4, 256);
    bool fast = (off <= ws_size) && (B <= MAXB);

    if (fast) {
        int pgrid = (N + 511) / 512;
        prep_kernel<<<pgrid, 512, 0, stream>>>(x, pos, xpos, delta_extra,
                                               g_ptr64, ovf_cnt, N, PB);
        int sgrid = (E + BLK_SC * RPT_SC - 1) / (BLK_SC * RPT_SC);   // 250
        scatter_kernel<<<sgrid, BLK_SC, 0, stream>>>(srcs, dsts, E, B,
                                                     g_ptr64, sorted, ovf, ovf_cnt);
        compute_kernel<<<KPART * B, BLK_C, 0, stream>>>(xpos, mlp_w, mlp_b, head_w,
                                                        sorted, g_ptr64, partial, BB);
        ovf_kernel<<<16, 256, 0, stream>>>(x, pos, mlp_w, mlp_b, head_w,
                                           ovf, ovf_cnt, delta_extra);
        final_kernel<<<(N + 511) / 512, 512, 0, stream>>>(
            (const float*)x, partial, BB, delta_extra, head_b, (float*)d_out, N);
    } else {
        float* delta = (float*)d_ws;
        hipMemsetAsync(delta, 0, (size_t)N * sizeof(float), stream);
        edge_kernel_fallback<<<(int)((E + 255) / 256), 256, 0, stream>>>(
            x, pos, mlp_w, mlp_b, head_w, srcs, dsts, delta, E);
        node_kernel_fallback<<<(N + 255) / 256, 256, 0, stream>>>(
            (const float*)x, delta, head_b, (float*)d_out, N);
    }
}